// Round 5
// baseline (330.205 us; speedup 1.0000x reference)
//
#include <hip/hip_runtime.h>
#include <stdint.h>

#define DM   1024
#define HD   64
#define SEQ  2048
#define NB   4
#define MR   8192   // NB*SEQ

typedef __bf16  bf16x8 __attribute__((ext_vector_type(8)));
typedef float   f32x4  __attribute__((ext_vector_type(4)));
typedef unsigned short u16x8 __attribute__((ext_vector_type(8)));

__device__ __forceinline__ unsigned short f2bf(float f) {
  union { float f; unsigned u; } x; x.f = f;
  unsigned u = x.u + 0x7fffu + ((x.u >> 16) & 1u);   // RTNE
  return (unsigned short)(u >> 16);
}

// pack two f32 -> (bf16(a) | bf16(b)<<16), round-half-up via +0x8000 then v_perm
__device__ __forceinline__ unsigned pk_bf16(float a, float b) {
  unsigned ua = __builtin_bit_cast(unsigned, a) + 0x8000u;
  unsigned ub = __builtin_bit_cast(unsigned, b) + 0x8000u;
  return __builtin_amdgcn_perm(ub, ua, 0x07060302);  // [ua.b2,ua.b3,ub.b2,ub.b3]
}

// raw v_exp_f32 (exp2). ocml exp2f is a multi-instruction call -- avoid it.
__device__ __forceinline__ float fexp2(float x) {
#if __has_builtin(__builtin_amdgcn_exp2f)
  return __builtin_amdgcn_exp2f(x);
#else
  float r; asm("v_exp_f32 %0, %1" : "=v"(r) : "v"(x)); return r;
#endif
}

__device__ __forceinline__ void gld_lds16(const void* g, void* l) {
  __builtin_amdgcn_global_load_lds((const __attribute__((address_space(1))) unsigned int*)g,
                                   (__attribute__((address_space(3))) unsigned int*)l, 16, 0, 0);
}

// ---------------- prep kernels ----------------
__global__ __launch_bounds__(256) void cvt3(const float* __restrict__ a, const float* __restrict__ b,
                                            const float* __restrict__ c, unsigned short* __restrict__ oa,
                                            unsigned short* __restrict__ ob, unsigned short* __restrict__ oc) {
  const float* in = (blockIdx.z == 0) ? a : (blockIdx.z == 1) ? b : c;
  unsigned short* out = (blockIdx.z == 0) ? oa : (blockIdx.z == 1) ? ob : oc;
  size_t i = ((size_t)blockIdx.x * 256 + threadIdx.x) * 8;
  float4 x = *(const float4*)(in + i);
  float4 y = *(const float4*)(in + i + 4);
  u16x8 r = { f2bf(x.x), f2bf(x.y), f2bf(x.z), f2bf(x.w), f2bf(y.x), f2bf(y.y), f2bf(y.z), f2bf(y.w) };
  *(u16x8*)(out + i) = r;
}

// Wq/Wk/Wv [H, D, hd] -> Wt[z][n = h*64+k][d] bf16, coalesced via 64x65 LDS tile.
__global__ __launch_bounds__(256) void wtrans(const float* __restrict__ wq, const float* __restrict__ wk,
                                              const float* __restrict__ wv, unsigned short* __restrict__ wt) {
  __shared__ float tile[64 * 65];
  const float* in = (blockIdx.z == 0) ? wq : (blockIdx.z == 1) ? wk : wv;
  unsigned short* out = wt + ((size_t)blockIdx.z << 20);
  const int h = blockIdx.x >> 4, d0 = (blockIdx.x & 15) * 64;
  const int tid = threadIdx.x;
  const int k = tid & 63, rr = tid >> 6;
#pragma unroll
  for (int j = 0; j < 16; ++j) {
    int row = rr + j * 4;
    tile[row * 65 + k] = in[h * 65536 + (d0 + row) * 64 + k];
  }
  __syncthreads();
  const int dd = tid & 63, kr = tid >> 6;
#pragma unroll
  for (int j = 0; j < 16; ++j) {
    int kk = kr + j * 4;
    out[(size_t)(h * 64 + kk) * 1024 + d0 + dd] = f2bf(tile[dd * 65 + kk]);
  }
}

__global__ __launch_bounds__(256) void cvt1(const float* __restrict__ in, unsigned short* __restrict__ out) {
  size_t i = ((size_t)blockIdx.x * 256 + threadIdx.x) * 8;
  float4 x = *(const float4*)(in + i);
  float4 y = *(const float4*)(in + i + 4);
  u16x8 r = { f2bf(x.x), f2bf(x.y), f2bf(x.z), f2bf(x.w), f2bf(y.x), f2bf(y.y), f2bf(y.z), f2bf(y.w) };
  *(u16x8*)(out + i) = r;
}

// ---------------- GEMM: C[M,N] = A[M,K] * Bt[N,K]^T ----------------
// round-0 proven kernel + XCD-aware bijective block swizzle (512 blocks % 8 == 0):
// the 8 bn-blocks sharing an A-panel land on one XCD -> A panel resident in one L2.
template <bool BF16OUT>
__global__ __launch_bounds__(256, 2) void gemm_bt(
    const unsigned short* __restrict__ A0, const unsigned short* __restrict__ A1,
    const unsigned short* __restrict__ A2, const unsigned short* __restrict__ Bt,
    void* __restrict__ Cv, const float* __restrict__ bias) {
  __shared__ char lds[32768];
  char* ldsA = lds;
  char* ldsB = lds + 16384;

  const int tid = threadIdx.x, w = tid >> 6, l = tid & 63;
  const int quad = l >> 4, l15 = l & 15;
  const int z = blockIdx.z;
  const unsigned short* A = (z == 0) ? A0 : (z == 1) ? A1 : A2;
  const unsigned short* B = Bt + (size_t)z * (DM * DM);
  // XCD swizzle: lin%8 ~ XCD (dispatch round-robin); give each XCD a
  // contiguous run of bm-panels. Bijective: 512 % 8 == 0.
  const int lin = blockIdx.y * 8 + blockIdx.x;
  const int swz = (lin & 7) * 64 + (lin >> 3);
  const int bm = (swz >> 3) * 128, bn = (swz & 7) * 128;
  const int wrow = (w >> 1) * 64, wcol = (w & 1) * 64;

  const int srow = w * 32 + (l >> 3);
  const int sc   = ((l & 7) ^ ((l >> 3) & 7)) * 8;
  char* ldsAw = ldsA + (w * 32) * 128;
  char* ldsBw = ldsB + (w * 32) * 128;

  f32x4 acc[4][4];
#pragma unroll
  for (int i = 0; i < 4; ++i)
#pragma unroll
    for (int j = 0; j < 4; ++j) acc[i][j] = (f32x4){0.f, 0.f, 0.f, 0.f};

  for (int kt = 0; kt < DM; kt += 64) {
#pragma unroll
    for (int p = 0; p < 4; ++p) {
      gld_lds16(A + (size_t)(bm + srow + p * 8) * DM + kt + sc, ldsAw + p * 1024);
      gld_lds16(B + (size_t)(bn + srow + p * 8) * DM + kt + sc, ldsBw + p * 1024);
    }
    __syncthreads();
#pragma unroll
    for (int ks = 0; ks < 2; ++ks) {
      bf16x8 af[4], bfr[4];
#pragma unroll
      for (int mt = 0; mt < 4; ++mt) {
        int r = wrow + mt * 16 + l15;
        af[mt] = *(const bf16x8*)(ldsA + r * 128 + (((ks * 4 + quad) ^ (r & 7)) * 16));
      }
#pragma unroll
      for (int nt = 0; nt < 4; ++nt) {
        int r = wcol + nt * 16 + l15;
        bfr[nt] = *(const bf16x8*)(ldsB + r * 128 + (((ks * 4 + quad) ^ (r & 7)) * 16));
      }
#pragma unroll
      for (int mt = 0; mt < 4; ++mt)
#pragma unroll
        for (int nt = 0; nt < 4; ++nt)
          acc[mt][nt] = __builtin_amdgcn_mfma_f32_16x16x32_bf16(af[mt], bfr[nt], acc[mt][nt], 0, 0, 0);
    }
    __syncthreads();
  }

  if constexpr (BF16OUT) {
    unsigned short* C = (unsigned short*)Cv + (size_t)z * ((size_t)MR * DM);
#pragma unroll
    for (int mt = 0; mt < 4; ++mt)
#pragma unroll
      for (int r = 0; r < 4; ++r) {
        size_t row = bm + wrow + mt * 16 + quad * 4 + r;
#pragma unroll
        for (int nt = 0; nt < 4; ++nt)
          C[row * DM + bn + wcol + nt * 16 + l15] = f2bf(acc[mt][nt][r]);
      }
  } else {
    float* C = (float*)Cv;
    float bv[4];
#pragma unroll
    for (int nt = 0; nt < 4; ++nt) bv[nt] = bias[bn + wcol + nt * 16 + l15];
#pragma unroll
    for (int mt = 0; mt < 4; ++mt)
#pragma unroll
      for (int r = 0; r < 4; ++r) {
        size_t row = bm + wrow + mt * 16 + quad * 4 + r;
#pragma unroll
        for (int nt = 0; nt < 4; ++nt)
          C[row * DM + bn + wcol + nt * 16 + l15] = acc[mt][nt][r] + bv[nt];
      }
  }
}

// ---------------- flash attention v8: occupancy boost ----------------
// Same proven math/layout as the passing v4+T1/T5 kernel, but q-tile halved
// (128 rows/block, 16/wave, mt loop removed) so per-wave P shrinks to 2KB:
// LDS 64KB -> 48KB => 3 blocks/CU (24 waves/CU vs 16). Grid doubles to
// 1024 blocks (16 qt x 64 bh). Per-q accumulation order is bit-identical.
// Diagnosis: MfmaUtil 37 / VALUBusy 54 / Occupancy 35, HBM 6.5% ->
// latency-bound; more resident waves per SIMD cover the dependent
// MFMA->exp->pack->LDS chain.
__global__ __launch_bounds__(512, 6) void attn_flash(
    const unsigned short* __restrict__ Qp, const unsigned short* __restrict__ Kp,
    const unsigned short* __restrict__ Vp, unsigned short* __restrict__ Ctx) {
  __shared__ char lds[49152];
  char* ldsK  = lds;            // 2 x 8KB: K[64 t][64 k] swizzled, 128B rows
  char* ldsVt = lds + 16384;    // 2 x 8KB: V^T[64 n][64 t] swizzled, 128B rows
  char* ldsP  = lds + 32768;    // 8 x 2KB: per-wave P[16 q][64 t] swizzled

  const int tid = threadIdx.x, w = tid >> 6, l = tid & 63;
  const int quad = l >> 4, l15 = l & 15;
  // XCD swizzle (bijective, 1024 blocks): XCD k owns bh in [8k, 8k+8), all qt.
  const int lin = blockIdx.y * 16 + blockIdx.x;
  const int swz = (lin & 7) * 128 + (lin >> 3);
  const int qt = swz & 15, bh = swz >> 4;
  const int b = bh >> 4, h = bh & 15;
  const size_t rb = (size_t)b * SEQ;
  const int hc = h * HD;

  // Q fragments (B-operand): lane holds Q[q = q0+l15][k = ks*32+quad*8+j]
  bf16x8 qf[2];
  const int q0 = qt * 128 + w * 16;
#pragma unroll
  for (int ks = 0; ks < 2; ++ks)
    qf[ks] = *(const bf16x8*)(Qp + (rb + q0 + l15) * DM + hc + ks * 32 + quad * 8);

  f32x4 o[4], l_acc;
  l_acc = (f32x4){0.f, 0.f, 0.f, 0.f};
#pragma unroll
  for (int nt = 0; nt < 4; ++nt) o[nt] = (f32x4){0.f, 0.f, 0.f, 0.f};

  const int sc = ((l & 7) ^ (l >> 3)) * 8;     // K staging swizzle (elems)
  const float c2 = 0.045084220027780106f;      // (1/sqrt(1024)) * log2(e)
  char* prow = ldsP + w * 2048;                // wave-private P region

  const u16x8 ones_u = {0x3f80, 0x3f80, 0x3f80, 0x3f80, 0x3f80, 0x3f80, 0x3f80, 0x3f80};
  const bf16x8 ones = __builtin_bit_cast(bf16x8, ones_u);

  // preload tile 0 into buffer 0 (K: one gld_lds16/thread; V: row t=l, cols w*8..w*8+7)
  {
    gld_lds16(Kp + (rb + w * 8 + (l >> 3)) * DM + hc + sc, ldsK + w * 1024);
    u16x8 vr = *(const u16x8*)(Vp + (rb + l) * DM + hc + w * 8);
#pragma unroll
    for (int i = 0; i < 8; ++i) {
      int n = w * 8 + i;
      *(unsigned short*)(ldsVt + n * 128 + (((l >> 3) ^ i) * 16) + (l & 7) * 2) = vr[i];
    }
  }

  for (int kt = 0; kt < SEQ / 64; ++kt) {
    const int kb = kt & 1;
    char* ldsKb = ldsK + kb * 8192;
    char* ldsVb = ldsVt + kb * 8192;
    __syncthreads();   // staging of buf[kb] complete; all waves left iter kt-1

    // issue staging for kt+1 into the other buffer (latency hidden by compute)
    u16x8 vr;
    const bool pre = (kt < SEQ / 64 - 1);
    if (pre) {
      const size_t krow = rb + (size_t)(kt + 1) * 64;
      gld_lds16(Kp + (krow + w * 8 + (l >> 3)) * DM + hc + sc, ldsK + (kb ^ 1) * 8192 + w * 1024);
      vr = *(const u16x8*)(Vp + (krow + l) * DM + hc + w * 8);
    }

    // S^T = K Q^T : lane holds S^T[t=ct*16+quad*4+r][q=q0+l15]
    f32x4 s[4];
#pragma unroll
    for (int ct = 0; ct < 4; ++ct) s[ct] = (f32x4){0.f, 0.f, 0.f, 0.f};
    __builtin_amdgcn_s_setprio(1);
#pragma unroll
    for (int ks = 0; ks < 2; ++ks)
#pragma unroll
      for (int ct = 0; ct < 4; ++ct) {
        int rt = ct * 16 + l15;
        bf16x8 kf = *(const bf16x8*)(ldsKb + rt * 128 + (((ks * 4 + quad) ^ (rt & 7)) * 16));
        s[ct] = __builtin_amdgcn_mfma_f32_16x16x32_bf16(kf, qf[ks], s[ct], 0, 0, 0);
      }
    __builtin_amdgcn_s_setprio(0);

    // fixed-max softmax: p = exp2(s*c2 - 2); pack; write P to wave-private LDS
    {
      char* pr = prow + l15 * 128;
      const int co = quad >> 1, bo = (quad & 1) * 8;
#pragma unroll
      for (int ct = 0; ct < 4; ++ct) {
        float p0 = fexp2(__builtin_fmaf(s[ct][0], c2, -2.0f));
        float p1 = fexp2(__builtin_fmaf(s[ct][1], c2, -2.0f));
        float p2 = fexp2(__builtin_fmaf(s[ct][2], c2, -2.0f));
        float p3 = fexp2(__builtin_fmaf(s[ct][3], c2, -2.0f));
        unsigned lo = pk_bf16(p0, p1), hi = pk_bf16(p2, p3);
        unsigned long long pw = (unsigned long long)lo | ((unsigned long long)hi << 32);
        int c = 2 * ct + co;   // t0 = ct*16 + quad*4 -> chunk
        *(unsigned long long*)(pr + ((c ^ (l15 & 7)) * 16) + bo) = pw;
      }
    }

    // O += P V ; l += P * ones (row-sum on the matrix pipe)
    __builtin_amdgcn_s_setprio(1);
#pragma unroll
    for (int ks = 0; ks < 2; ++ks) {
      bf16x8 pf0 = *(const bf16x8*)(prow + l15 * 128 + (((ks * 4 + quad) ^ (l15 & 7)) * 16));
      l_acc = __builtin_amdgcn_mfma_f32_16x16x32_bf16(pf0, ones, l_acc, 0, 0, 0);
#pragma unroll
      for (int nt = 0; nt < 4; ++nt) {
        int n = nt * 16 + l15;
        bf16x8 vf = *(const bf16x8*)(ldsVb + n * 128 + (((ks * 4 + quad) ^ (n & 7)) * 16));
        o[nt] = __builtin_amdgcn_mfma_f32_16x16x32_bf16(pf0, vf, o[nt], 0, 0, 0);
      }
    }
    __builtin_amdgcn_s_setprio(0);

    // transpose-write V(kt+1) into the other buffer (safe: all waves past barrier kt)
    if (pre) {
      char* vb = ldsVt + (kb ^ 1) * 8192;
#pragma unroll
      for (int i = 0; i < 8; ++i) {
        int n = w * 8 + i;
        *(unsigned short*)(vb + n * 128 + (((l >> 3) ^ i) * 16) + (l & 7) * 2) = vr[i];
      }
    }
  }

  // epilogue: normalize by l (ones-B makes all 16 output cols identical in l_acc)
#pragma unroll
  for (int r = 0; r < 4; ++r) {
    float inv = 1.f / l_acc[r];
    size_t row = rb + q0 + quad * 4 + r;
#pragma unroll
    for (int nt = 0; nt < 4; ++nt)
      Ctx[row * DM + hc + nt * 16 + l15] = f2bf(o[nt][r] * inv);
  }
}

// ---------------- launch ----------------
extern "C" void kernel_launch(void* const* d_in, const int* in_sizes, int n_in,
                              void* d_out, int out_size, void* d_ws, size_t ws_size,
                              hipStream_t stream) {
  const float* query  = (const float*)d_in[0];
  const float* key_in = (const float*)d_in[1];
  const float* value  = (const float*)d_in[2];
  const float* Wq = (const float*)d_in[3];
  const float* Wk = (const float*)d_in[4];
  const float* Wv = (const float*)d_in[5];
  const float* Wo = (const float*)d_in[6];
  const float* bo = (const float*)d_in[7];
  float* out = (float*)d_out;

  unsigned short* ws = (unsigned short*)d_ws;
  const size_t NT = (size_t)MR * DM;   // 8388608 elems
  unsigned short* Xq  = ws;
  unsigned short* Xk  = Xq + NT;
  unsigned short* Xv  = Xk + NT;
  unsigned short* Wt  = Xv + NT;              // 3 * 1M
  unsigned short* Wob = Wt + 3 * 1048576;     // 1M
  unsigned short* Qb  = Wob + 1048576;
  unsigned short* Kb  = Qb + NT;
  unsigned short* Vb  = Kb + NT;
  unsigned short* Cx  = Vb + NT;

  cvt3<<<dim3(4096, 1, 3), 256, 0, stream>>>(query, key_in, value, Xq, Xk, Xv);
  wtrans<<<dim3(256, 1, 3), 256, 0, stream>>>(Wq, Wk, Wv, Wt);
  cvt1<<<dim3(512, 1, 1), 256, 0, stream>>>(Wo, Wob);
  gemm_bt<true><<<dim3(8, 64, 3), 256, 0, stream>>>(Xq, Xk, Xv, Wt, Qb, nullptr);
  attn_flash<<<dim3(16, 64), 512, 0, stream>>>(Qb, Kb, Vb, Cx);
  gemm_bt<false><<<dim3(8, 64, 1), 256, 0, stream>>>(Cx, Cx, Cx, Wob, out, bo);
}

// Round 6
// 303.230 us; speedup vs baseline: 1.0890x; 1.0890x over previous
//
#include <hip/hip_runtime.h>
#include <stdint.h>

#define DM   1024
#define HD   64
#define SEQ  2048
#define NB   4
#define MR   8192   // NB*SEQ

typedef __bf16  bf16x8 __attribute__((ext_vector_type(8)));
typedef float   f32x4  __attribute__((ext_vector_type(4)));
typedef unsigned short u16x8 __attribute__((ext_vector_type(8)));

__device__ __forceinline__ unsigned short f2bf(float f) {
  union { float f; unsigned u; } x; x.f = f;
  unsigned u = x.u + 0x7fffu + ((x.u >> 16) & 1u);   // RTNE
  return (unsigned short)(u >> 16);
}

// pack two f32 -> (bf16(a) | bf16(b)<<16), round-half-up via +0x8000 then v_perm
__device__ __forceinline__ unsigned pk_bf16(float a, float b) {
  unsigned ua = __builtin_bit_cast(unsigned, a) + 0x8000u;
  unsigned ub = __builtin_bit_cast(unsigned, b) + 0x8000u;
  return __builtin_amdgcn_perm(ub, ua, 0x07060302);  // [ua.b2,ua.b3,ub.b2,ub.b3]
}

// raw v_exp_f32 (exp2). ocml exp2f is a multi-instruction call -- avoid it.
__device__ __forceinline__ float fexp2(float x) {
#if __has_builtin(__builtin_amdgcn_exp2f)
  return __builtin_amdgcn_exp2f(x);
#else
  float r; asm("v_exp_f32 %0, %1" : "=v"(r) : "v"(x)); return r;
#endif
}

__device__ __forceinline__ void gld_lds16(const void* g, void* l) {
  __builtin_amdgcn_global_load_lds((const __attribute__((address_space(1))) unsigned int*)g,
                                   (__attribute__((address_space(3))) unsigned int*)l, 16, 0, 0);
}

// ---------------- merged prep kernel ----------------
// z<3: cvt3 (4096 blocks x). z==3: x<768 wtrans (3x256), 768<=x<1280 cvt1 (512).
// Bodies are bit-identical to the previously separate kernels; merging removes
// two dispatch gaps.
__global__ __launch_bounds__(256) void prep(
    const float* __restrict__ qf32, const float* __restrict__ kf32, const float* __restrict__ vf32,
    unsigned short* __restrict__ xq, unsigned short* __restrict__ xk, unsigned short* __restrict__ xv,
    const float* __restrict__ wq, const float* __restrict__ wk, const float* __restrict__ wv,
    unsigned short* __restrict__ wt, const float* __restrict__ wo, unsigned short* __restrict__ wob) {
  __shared__ float tile[64 * 65];
  const int z = blockIdx.z, tid = threadIdx.x;
  if (z < 3) {
    const float* in = (z == 0) ? qf32 : (z == 1) ? kf32 : vf32;
    unsigned short* out = (z == 0) ? xq : (z == 1) ? xk : xv;
    size_t i = ((size_t)blockIdx.x * 256 + tid) * 8;
    float4 x = *(const float4*)(in + i);
    float4 y = *(const float4*)(in + i + 4);
    u16x8 r = { f2bf(x.x), f2bf(x.y), f2bf(x.z), f2bf(x.w), f2bf(y.x), f2bf(y.y), f2bf(y.z), f2bf(y.w) };
    *(u16x8*)(out + i) = r;
    return;
  }
  const int bx = blockIdx.x;
  if (bx < 768) {   // wtrans: Wq/Wk/Wv [H, D, hd] -> Wt[zz][h*64+k][d] bf16
    const int zz = bx >> 8, bb = bx & 255;
    const float* in = (zz == 0) ? wq : (zz == 1) ? wk : wv;
    unsigned short* out = wt + ((size_t)zz << 20);
    const int h = bb >> 4, d0 = (bb & 15) * 64;
    const int k = tid & 63, rr = tid >> 6;
#pragma unroll
    for (int j = 0; j < 16; ++j) {
      int row = rr + j * 4;
      tile[row * 65 + k] = in[h * 65536 + (d0 + row) * 64 + k];
    }
    __syncthreads();
    const int dd = tid & 63, kr = tid >> 6;
#pragma unroll
    for (int j = 0; j < 16; ++j) {
      int k2 = kr + j * 4;
      out[(size_t)(h * 64 + k2) * 1024 + d0 + dd] = f2bf(tile[dd * 65 + k2]);
    }
  } else if (bx < 1280) {   // cvt1: Wo f32 -> bf16
    size_t i = ((size_t)(bx - 768) * 256 + tid) * 8;
    float4 x = *(const float4*)(wo + i);
    float4 y = *(const float4*)(wo + i + 4);
    u16x8 r = { f2bf(x.x), f2bf(x.y), f2bf(x.z), f2bf(x.w), f2bf(y.x), f2bf(y.y), f2bf(y.z), f2bf(y.w) };
    *(u16x8*)(wob + i) = r;
  }
}

// ---------------- GEMM: C[M,N] = A[M,K] * Bt[N,K]^T ----------------
// v2: single-barrier double-buffered staging (T3-minimum). Prefetch of tile
// kt+1 is issued BEFORE the MFMA block of tile kt; the one __syncthreads per
// iteration drains vmcnt (documented __syncthreads semantics: full
// vmcnt(0)+lgkmcnt(0) drain before s_barrier), so the DMA is complete and all
// waves are done reading the old buffer before it is overwritten.
// LDS 64KB (2x{A16K|B16K}) -> 2 blocks/CU. XCD swizzle unchanged (proven R4).
template <bool BF16OUT>
__global__ __launch_bounds__(256, 2) void gemm_bt(
    const unsigned short* __restrict__ A0, const unsigned short* __restrict__ A1,
    const unsigned short* __restrict__ A2, const unsigned short* __restrict__ Bt,
    void* __restrict__ Cv, const float* __restrict__ bias) {
  __shared__ char lds[65536];

  const int tid = threadIdx.x, w = tid >> 6, l = tid & 63;
  const int quad = l >> 4, l15 = l & 15;
  const int z = blockIdx.z;
  const unsigned short* A = (z == 0) ? A0 : (z == 1) ? A1 : A2;
  const unsigned short* B = Bt + (size_t)z * (DM * DM);
  // XCD swizzle: lin%8 ~ XCD (dispatch round-robin); bijective (512 % 8 == 0).
  const int lin = blockIdx.y * 8 + blockIdx.x;
  const int swz = (lin & 7) * 64 + (lin >> 3);
  const int bm = (swz >> 3) * 128, bn = (swz & 7) * 128;
  const int wrow = (w >> 1) * 64, wcol = (w & 1) * 64;

  const int srow = w * 32 + (l >> 3);
  const int sc   = ((l & 7) ^ ((l >> 3) & 7)) * 8;

  f32x4 acc[4][4];
#pragma unroll
  for (int i = 0; i < 4; ++i)
#pragma unroll
    for (int j = 0; j < 4; ++j) acc[i][j] = (f32x4){0.f, 0.f, 0.f, 0.f};

#define STAGEG(buf, kt) do {                                                   \
    char* dA = lds + (buf) * 32768 + (w * 32) * 128;                           \
    char* dB = dA + 16384;                                                     \
    _Pragma("unroll")                                                          \
    for (int p = 0; p < 4; ++p) {                                              \
      gld_lds16(A + (size_t)(bm + srow + p * 8) * DM + (kt) + sc, dA + p * 1024); \
      gld_lds16(B + (size_t)(bn + srow + p * 8) * DM + (kt) + sc, dB + p * 1024); \
    } } while (0)

  STAGEG(0, 0);
  __syncthreads();   // drains prologue DMA (vmcnt(0) before s_barrier)
  int cur = 0;

  for (int kt = 0; kt < DM; kt += 64) {
    if (kt + 64 < DM) STAGEG(cur ^ 1, kt + 64);   // prefetch next tile
    char* ldsA = lds + cur * 32768;
    char* ldsB = ldsA + 16384;
#pragma unroll
    for (int ks = 0; ks < 2; ++ks) {
      bf16x8 af[4], bfr[4];
#pragma unroll
      for (int mt = 0; mt < 4; ++mt) {
        int r = wrow + mt * 16 + l15;
        af[mt] = *(const bf16x8*)(ldsA + r * 128 + (((ks * 4 + quad) ^ (r & 7)) * 16));
      }
#pragma unroll
      for (int nt = 0; nt < 4; ++nt) {
        int r = wcol + nt * 16 + l15;
        bfr[nt] = *(const bf16x8*)(ldsB + r * 128 + (((ks * 4 + quad) ^ (r & 7)) * 16));
      }
#pragma unroll
      for (int mt = 0; mt < 4; ++mt)
#pragma unroll
        for (int nt = 0; nt < 4; ++nt)
          acc[mt][nt] = __builtin_amdgcn_mfma_f32_16x16x32_bf16(af[mt], bfr[nt], acc[mt][nt], 0, 0, 0);
    }
    __syncthreads();   // prefetch DMA complete + all waves done reading cur
    cur ^= 1;
  }
#undef STAGEG

  if constexpr (BF16OUT) {
    unsigned short* C = (unsigned short*)Cv + (size_t)z * ((size_t)MR * DM);
#pragma unroll
    for (int mt = 0; mt < 4; ++mt)
#pragma unroll
      for (int r = 0; r < 4; ++r) {
        size_t row = bm + wrow + mt * 16 + quad * 4 + r;
#pragma unroll
        for (int nt = 0; nt < 4; ++nt)
          C[row * DM + bn + wcol + nt * 16 + l15] = f2bf(acc[mt][nt][r]);
      }
  } else {
    float* C = (float*)Cv;
    float bv[4];
#pragma unroll
    for (int nt = 0; nt < 4; ++nt) bv[nt] = bias[bn + wcol + nt * 16 + l15];
#pragma unroll
    for (int mt = 0; mt < 4; ++mt)
#pragma unroll
      for (int r = 0; r < 4; ++r) {
        size_t row = bm + wrow + mt * 16 + quad * 4 + r;
#pragma unroll
        for (int nt = 0; nt < 4; ++nt)
          C[row * DM + bn + wcol + nt * 16 + l15] = acc[mt][nt][r] + bv[nt];
      }
  }
}

// ---------------- flash attention (round-4 proven version, verbatim) ----------------
// 256 q-rows/block (32/wave): amortizes per-iter staging+barrier overhead --
// round-5 showed halving the tile (despite +15pp occupancy) costs 17% because
// staging work per block-iteration is constant. Do not shrink the q-tile.
__global__ __launch_bounds__(512, 4) void attn_flash(
    const unsigned short* __restrict__ Qp, const unsigned short* __restrict__ Kp,
    const unsigned short* __restrict__ Vp, unsigned short* __restrict__ Ctx) {
  __shared__ char lds[65536];
  char* ldsK  = lds;            // 2 x 8KB: K[64 t][64 k] swizzled, 128B rows
  char* ldsVt = lds + 16384;    // 2 x 8KB: V^T[64 n][64 t] swizzled, 128B rows
  char* ldsP  = lds + 32768;    // 8 x 4KB: per-wave P[32 q][64 t] swizzled

  const int tid = threadIdx.x, w = tid >> 6, l = tid & 63;
  const int quad = l >> 4, l15 = l & 15;
  // XCD swizzle (bijective, 512 blocks): XCD k owns bh in [8k, 8k+8), all qt.
  const int lin = blockIdx.y * 8 + blockIdx.x;
  const int swz = (lin & 7) * 64 + (lin >> 3);
  const int qt = swz & 7, bh = swz >> 3;
  const int b = bh >> 4, h = bh & 15;
  const size_t rb = (size_t)b * SEQ;
  const int hc = h * HD;

  // Q fragments (B-operand): lane holds Q[q = q0+mt*16+l15][k = ks*32+quad*8+j]
  bf16x8 qf[2][2];
  const int q0 = qt * 256 + w * 32;
#pragma unroll
  for (int mt = 0; mt < 2; ++mt)
#pragma unroll
    for (int ks = 0; ks < 2; ++ks)
      qf[mt][ks] = *(const bf16x8*)(Qp + (rb + q0 + mt * 16 + l15) * DM + hc + ks * 32 + quad * 8);

  f32x4 o[2][4], l_acc[2];
#pragma unroll
  for (int mt = 0; mt < 2; ++mt) {
    l_acc[mt] = (f32x4){0.f, 0.f, 0.f, 0.f};
#pragma unroll
    for (int nt = 0; nt < 4; ++nt) o[mt][nt] = (f32x4){0.f, 0.f, 0.f, 0.f};
  }

  const int sc = ((l & 7) ^ (l >> 3)) * 8;     // K staging swizzle (elems)
  const float c2 = 0.045084220027780106f;      // (1/sqrt(1024)) * log2(e)
  char* prow = ldsP + w * 4096;                // wave-private P region

  const u16x8 ones_u = {0x3f80, 0x3f80, 0x3f80, 0x3f80, 0x3f80, 0x3f80, 0x3f80, 0x3f80};
  const bf16x8 ones = __builtin_bit_cast(bf16x8, ones_u);

  // preload tile 0 into buffer 0 (K: one gld_lds16/thread; V: row t=l, cols w*8..w*8+7)
  {
    gld_lds16(Kp + (rb + w * 8 + (l >> 3)) * DM + hc + sc, ldsK + w * 1024);
    u16x8 vr = *(const u16x8*)(Vp + (rb + l) * DM + hc + w * 8);
#pragma unroll
    for (int i = 0; i < 8; ++i) {
      int n = w * 8 + i;
      *(unsigned short*)(ldsVt + n * 128 + (((l >> 3) ^ i) * 16) + (l & 7) * 2) = vr[i];
    }
  }

  for (int kt = 0; kt < SEQ / 64; ++kt) {
    const int kb = kt & 1;
    char* ldsKb = ldsK + kb * 8192;
    char* ldsVb = ldsVt + kb * 8192;
    __syncthreads();   // staging of buf[kb] complete; all waves left iter kt-1

    // issue staging for kt+1 into the other buffer (latency hidden by compute)
    u16x8 vr;
    const bool pre = (kt < SEQ / 64 - 1);
    if (pre) {
      const size_t krow = rb + (size_t)(kt + 1) * 64;
      gld_lds16(Kp + (krow + w * 8 + (l >> 3)) * DM + hc + sc, ldsK + (kb ^ 1) * 8192 + w * 1024);
      vr = *(const u16x8*)(Vp + (krow + l) * DM + hc + w * 8);
    }

    // S^T = K Q^T : lane holds S^T[t=ct*16+quad*4+r][q=q0+mt*16+l15]
    f32x4 s[2][4];
#pragma unroll
    for (int mt = 0; mt < 2; ++mt)
#pragma unroll
      for (int ct = 0; ct < 4; ++ct) s[mt][ct] = (f32x4){0.f, 0.f, 0.f, 0.f};
    __builtin_amdgcn_s_setprio(1);
#pragma unroll
    for (int ks = 0; ks < 2; ++ks)
#pragma unroll
      for (int ct = 0; ct < 4; ++ct) {
        int rt = ct * 16 + l15;
        bf16x8 kf = *(const bf16x8*)(ldsKb + rt * 128 + (((ks * 4 + quad) ^ (rt & 7)) * 16));
        s[0][ct] = __builtin_amdgcn_mfma_f32_16x16x32_bf16(kf, qf[0][ks], s[0][ct], 0, 0, 0);
        s[1][ct] = __builtin_amdgcn_mfma_f32_16x16x32_bf16(kf, qf[1][ks], s[1][ct], 0, 0, 0);
      }
    __builtin_amdgcn_s_setprio(0);

    // fixed-max softmax: p = exp2(s*c2 - 2); pack; write P to wave-private LDS
#pragma unroll
    for (int mt = 0; mt < 2; ++mt) {
      char* pr = prow + (mt * 16 + l15) * 128;
      const int co = quad >> 1, bo = (quad & 1) * 8;
#pragma unroll
      for (int ct = 0; ct < 4; ++ct) {
        float p0 = fexp2(__builtin_fmaf(s[mt][ct][0], c2, -2.0f));
        float p1 = fexp2(__builtin_fmaf(s[mt][ct][1], c2, -2.0f));
        float p2 = fexp2(__builtin_fmaf(s[mt][ct][2], c2, -2.0f));
        float p3 = fexp2(__builtin_fmaf(s[mt][ct][3], c2, -2.0f));
        unsigned lo = pk_bf16(p0, p1), hi = pk_bf16(p2, p3);
        unsigned long long pw = (unsigned long long)lo | ((unsigned long long)hi << 32);
        int c = 2 * ct + co;   // t0 = ct*16 + quad*4 -> chunk
        *(unsigned long long*)(pr + ((c ^ (l15 & 7)) * 16) + bo) = pw;
      }
    }

    // O += P V ; l += P * ones (row-sum on the matrix pipe)
    __builtin_amdgcn_s_setprio(1);
#pragma unroll
    for (int ks = 0; ks < 2; ++ks) {
      bf16x8 pf0 = *(const bf16x8*)(prow + l15 * 128 + (((ks * 4 + quad) ^ (l15 & 7)) * 16));
      bf16x8 pf1 = *(const bf16x8*)(prow + (16 + l15) * 128 + (((ks * 4 + quad) ^ (l15 & 7)) * 16));
      l_acc[0] = __builtin_amdgcn_mfma_f32_16x16x32_bf16(pf0, ones, l_acc[0], 0, 0, 0);
      l_acc[1] = __builtin_amdgcn_mfma_f32_16x16x32_bf16(pf1, ones, l_acc[1], 0, 0, 0);
#pragma unroll
      for (int nt = 0; nt < 4; ++nt) {
        int n = nt * 16 + l15;
        bf16x8 vf = *(const bf16x8*)(ldsVb + n * 128 + (((ks * 4 + quad) ^ (n & 7)) * 16));
        o[0][nt] = __builtin_amdgcn_mfma_f32_16x16x32_bf16(pf0, vf, o[0][nt], 0, 0, 0);
        o[1][nt] = __builtin_amdgcn_mfma_f32_16x16x32_bf16(pf1, vf, o[1][nt], 0, 0, 0);
      }
    }
    __builtin_amdgcn_s_setprio(0);

    // transpose-write V(kt+1) into the other buffer (safe: all waves past barrier kt)
    if (pre) {
      char* vb = ldsVt + (kb ^ 1) * 8192;
#pragma unroll
      for (int i = 0; i < 8; ++i) {
        int n = w * 8 + i;
        *(unsigned short*)(vb + n * 128 + (((l >> 3) ^ i) * 16) + (l & 7) * 2) = vr[i];
      }
    }
  }

  // epilogue: normalize by l (ones-B makes all 16 output cols identical in l_acc)
#pragma unroll
  for (int mt = 0; mt < 2; ++mt) {
#pragma unroll
    for (int r = 0; r < 4; ++r) {
      float inv = 1.f / l_acc[mt][r];
      size_t row = rb + q0 + mt * 16 + quad * 4 + r;
#pragma unroll
      for (int nt = 0; nt < 4; ++nt)
        Ctx[row * DM + hc + nt * 16 + l15] = f2bf(o[mt][nt][r] * inv);
    }
  }
}

// ---------------- launch ----------------
extern "C" void kernel_launch(void* const* d_in, const int* in_sizes, int n_in,
                              void* d_out, int out_size, void* d_ws, size_t ws_size,
                              hipStream_t stream) {
  const float* query  = (const float*)d_in[0];
  const float* key_in = (const float*)d_in[1];
  const float* value  = (const float*)d_in[2];
  const float* Wq = (const float*)d_in[3];
  const float* Wk = (const float*)d_in[4];
  const float* Wv = (const float*)d_in[5];
  const float* Wo = (const float*)d_in[6];
  const float* bo = (const float*)d_in[7];
  float* out = (float*)d_out;

  unsigned short* ws = (unsigned short*)d_ws;
  const size_t NT = (size_t)MR * DM;   // 8388608 elems
  unsigned short* Xq  = ws;
  unsigned short* Xk  = Xq + NT;
  unsigned short* Xv  = Xk + NT;
  unsigned short* Wt  = Xv + NT;              // 3 * 1M
  unsigned short* Wob = Wt + 3 * 1048576;     // 1M
  unsigned short* Qb  = Wob + 1048576;
  unsigned short* Kb  = Qb + NT;
  unsigned short* Vb  = Kb + NT;
  unsigned short* Cx  = Vb + NT;

  prep<<<dim3(4096, 1, 4), 256, 0, stream>>>(query, key_in, value, Xq, Xk, Xv,
                                             Wq, Wk, Wv, Wt, Wo, Wob);
  gemm_bt<true><<<dim3(8, 64, 3), 256, 0, stream>>>(Xq, Xk, Xv, Wt, Qb, nullptr);
  attn_flash<<<dim3(8, 64), 512, 0, stream>>>(Qb, Kb, Vb, Cx);
  gemm_bt<false><<<dim3(8, 64, 1), 256, 0, stream>>>(Cx, Cx, Cx, Wob, out, bo);
}

// Round 7
// 294.005 us; speedup vs baseline: 1.1231x; 1.0314x over previous
//
#include <hip/hip_runtime.h>
#include <stdint.h>

#define DM   1024
#define HD   64
#define SEQ  2048
#define NB   4
#define MR   8192   // NB*SEQ

typedef __bf16  bf16x8 __attribute__((ext_vector_type(8)));
typedef float   f32x4  __attribute__((ext_vector_type(4)));
typedef unsigned short u16x8 __attribute__((ext_vector_type(8)));

__device__ __forceinline__ unsigned short f2bf(float f) {
  union { float f; unsigned u; } x; x.f = f;
  unsigned u = x.u + 0x7fffu + ((x.u >> 16) & 1u);   // RTNE
  return (unsigned short)(u >> 16);
}

// pack two f32 -> (bf16(a) | bf16(b)<<16) by TRUNCATION (1 v_perm, no adds).
// Safe for softmax P only: the downward bias is a common relative factor on
// numerator and denominator of o/l and cancels; random part ~3e-5 abs.
__device__ __forceinline__ unsigned pk_trunc(float a, float b) {
  unsigned ua = __builtin_bit_cast(unsigned, a);
  unsigned ub = __builtin_bit_cast(unsigned, b);
  return __builtin_amdgcn_perm(ub, ua, 0x07060302);  // [ua.b2,ua.b3,ub.b2,ub.b3]
}

// raw v_exp_f32 (exp2). ocml exp2f is a multi-instruction call -- avoid it.
__device__ __forceinline__ float fexp2(float x) {
#if __has_builtin(__builtin_amdgcn_exp2f)
  return __builtin_amdgcn_exp2f(x);
#else
  float r; asm("v_exp_f32 %0, %1" : "=v"(r) : "v"(x)); return r;
#endif
}

__device__ __forceinline__ void gld_lds16(const void* g, void* l) {
  __builtin_amdgcn_global_load_lds((const __attribute__((address_space(1))) unsigned int*)g,
                                   (__attribute__((address_space(3))) unsigned int*)l, 16, 0, 0);
}

// ---------------- merged prep kernel ----------------
// z<3: cvt3 (4096 blocks x). z==3: x<768 wtrans (3x256), 768<=x<1280 cvt1 (512).
__global__ __launch_bounds__(256) void prep(
    const float* __restrict__ qf32, const float* __restrict__ kf32, const float* __restrict__ vf32,
    unsigned short* __restrict__ xq, unsigned short* __restrict__ xk, unsigned short* __restrict__ xv,
    const float* __restrict__ wq, const float* __restrict__ wk, const float* __restrict__ wv,
    unsigned short* __restrict__ wt, const float* __restrict__ wo, unsigned short* __restrict__ wob) {
  __shared__ float tile[64 * 65];
  const int z = blockIdx.z, tid = threadIdx.x;
  if (z < 3) {
    const float* in = (z == 0) ? qf32 : (z == 1) ? kf32 : vf32;
    unsigned short* out = (z == 0) ? xq : (z == 1) ? xk : xv;
    size_t i = ((size_t)blockIdx.x * 256 + tid) * 8;
    float4 x = *(const float4*)(in + i);
    float4 y = *(const float4*)(in + i + 4);
    u16x8 r = { f2bf(x.x), f2bf(x.y), f2bf(x.z), f2bf(x.w), f2bf(y.x), f2bf(y.y), f2bf(y.z), f2bf(y.w) };
    *(u16x8*)(out + i) = r;
    return;
  }
  const int bx = blockIdx.x;
  if (bx < 768) {   // wtrans: Wq/Wk/Wv [H, D, hd] -> Wt[zz][h*64+k][d] bf16
    const int zz = bx >> 8, bb = bx & 255;
    const float* in = (zz == 0) ? wq : (zz == 1) ? wk : wv;
    unsigned short* out = wt + ((size_t)zz << 20);
    const int h = bb >> 4, d0 = (bb & 15) * 64;
    const int k = tid & 63, rr = tid >> 6;
#pragma unroll
    for (int j = 0; j < 16; ++j) {
      int row = rr + j * 4;
      tile[row * 65 + k] = in[h * 65536 + (d0 + row) * 64 + k];
    }
    __syncthreads();
    const int dd = tid & 63, kr = tid >> 6;
#pragma unroll
    for (int j = 0; j < 16; ++j) {
      int k2 = kr + j * 4;
      out[(size_t)(h * 64 + k2) * 1024 + d0 + dd] = f2bf(tile[dd * 65 + k2]);
    }
  } else if (bx < 1280) {   // cvt1: Wo f32 -> bf16
    size_t i = ((size_t)(bx - 768) * 256 + tid) * 8;
    float4 x = *(const float4*)(wo + i);
    float4 y = *(const float4*)(wo + i + 4);
    u16x8 r = { f2bf(x.x), f2bf(x.y), f2bf(x.z), f2bf(x.w), f2bf(y.x), f2bf(y.y), f2bf(y.z), f2bf(y.w) };
    *(u16x8*)(wob + i) = r;
  }
}

// ---------------- GEMM: C[M,N] = A[M,K] * Bt[N,K]^T ----------------
// Single-barrier dbuf staging (R6) + immediate-offset fragment reads:
// (wrow+mt*16+l15)&7 == l15&7, so the XOR swizzle term is mt/nt-independent;
// one base per ks + mt*2048 folds into ds_read offset immediates.
template <bool BF16OUT>
__global__ __launch_bounds__(256, 2) void gemm_bt(
    const unsigned short* __restrict__ A0, const unsigned short* __restrict__ A1,
    const unsigned short* __restrict__ A2, const unsigned short* __restrict__ Bt,
    void* __restrict__ Cv, const float* __restrict__ bias) {
  __shared__ char lds[65536];

  const int tid = threadIdx.x, w = tid >> 6, l = tid & 63;
  const int quad = l >> 4, l15 = l & 15;
  const int z = blockIdx.z;
  const unsigned short* A = (z == 0) ? A0 : (z == 1) ? A1 : A2;
  const unsigned short* B = Bt + (size_t)z * (DM * DM);
  // XCD swizzle: lin%8 ~ XCD (dispatch round-robin); bijective (512 % 8 == 0).
  const int lin = blockIdx.y * 8 + blockIdx.x;
  const int swz = (lin & 7) * 64 + (lin >> 3);
  const int bm = (swz >> 3) * 128, bn = (swz & 7) * 128;
  const int wrow = (w >> 1) * 64, wcol = (w & 1) * 64;

  const int srow = w * 32 + (l >> 3);
  const int sc   = ((l & 7) ^ ((l >> 3) & 7)) * 8;

  f32x4 acc[4][4];
#pragma unroll
  for (int i = 0; i < 4; ++i)
#pragma unroll
    for (int j = 0; j < 4; ++j) acc[i][j] = (f32x4){0.f, 0.f, 0.f, 0.f};

#define STAGEG(buf, kt) do {                                                   \
    char* dA = lds + (buf) * 32768 + (w * 32) * 128;                           \
    char* dB = dA + 16384;                                                     \
    _Pragma("unroll")                                                          \
    for (int p = 0; p < 4; ++p) {                                              \
      gld_lds16(A + (size_t)(bm + srow + p * 8) * DM + (kt) + sc, dA + p * 1024); \
      gld_lds16(B + (size_t)(bn + srow + p * 8) * DM + (kt) + sc, dB + p * 1024); \
    } } while (0)

  STAGEG(0, 0);
  __syncthreads();   // drains prologue DMA (vmcnt(0) before s_barrier)
  int cur = 0;

  for (int kt = 0; kt < DM; kt += 64) {
    if (kt + 64 < DM) STAGEG(cur ^ 1, kt + 64);   // prefetch next tile
    char* ldsA = lds + cur * 32768;
    char* ldsB = ldsA + 16384;
#pragma unroll
    for (int ks = 0; ks < 2; ++ks) {
      const int x = ((ks * 4 + quad) ^ (l15 & 7)) * 16;
      const char* abase = ldsA + (wrow + l15) * 128 + x;
      const char* bbase = ldsB + (wcol + l15) * 128 + x;
      bf16x8 af[4], bfr[4];
#pragma unroll
      for (int mt = 0; mt < 4; ++mt) af[mt] = *(const bf16x8*)(abase + mt * 2048);
#pragma unroll
      for (int nt = 0; nt < 4; ++nt) bfr[nt] = *(const bf16x8*)(bbase + nt * 2048);
#pragma unroll
      for (int mt = 0; mt < 4; ++mt)
#pragma unroll
        for (int nt = 0; nt < 4; ++nt)
          acc[mt][nt] = __builtin_amdgcn_mfma_f32_16x16x32_bf16(af[mt], bfr[nt], acc[mt][nt], 0, 0, 0);
    }
    __syncthreads();   // prefetch DMA complete + all waves done reading cur
    cur ^= 1;
  }
#undef STAGEG

  if constexpr (BF16OUT) {
    unsigned short* C = (unsigned short*)Cv + (size_t)z * ((size_t)MR * DM);
#pragma unroll
    for (int mt = 0; mt < 4; ++mt)
#pragma unroll
      for (int r = 0; r < 4; ++r) {
        size_t row = bm + wrow + mt * 16 + quad * 4 + r;
#pragma unroll
        for (int nt = 0; nt < 4; ++nt)
          C[row * DM + bn + wcol + nt * 16 + l15] = f2bf(acc[mt][nt][r]);
      }
  } else {
    float* C = (float*)Cv;
    float bv[4];
#pragma unroll
    for (int nt = 0; nt < 4; ++nt) bv[nt] = bias[bn + wcol + nt * 16 + l15];
#pragma unroll
    for (int mt = 0; mt < 4; ++mt)
#pragma unroll
      for (int r = 0; r < 4; ++r) {
        size_t row = bm + wrow + mt * 16 + quad * 4 + r;
#pragma unroll
        for (int nt = 0; nt < 4; ++nt)
          C[row * DM + bn + wcol + nt * 16 + l15] = acc[mt][nt][r] + bv[nt];
      }
  }
}

// ---------------- flash attention (R4-proven structure + VALU diet) ----------------
// 256 q-rows/block (R5 lesson: don't shrink the tile). Changes vs R6:
//  - truncation pack (pk_trunc): -32 VALU/iter, output delta ~3e-5 (bias
//    cancels in o/l).
//  - fragment reads via one hoisted base per ks + {ct,nt}*2048 immediate
//    offsets (byte-identical addresses; (ct*16+l15)&7 == l15&7).
__global__ __launch_bounds__(512, 4) void attn_flash(
    const unsigned short* __restrict__ Qp, const unsigned short* __restrict__ Kp,
    const unsigned short* __restrict__ Vp, unsigned short* __restrict__ Ctx) {
  __shared__ char lds[65536];
  char* ldsK  = lds;            // 2 x 8KB: K[64 t][64 k] swizzled, 128B rows
  char* ldsVt = lds + 16384;    // 2 x 8KB: V^T[64 n][64 t] swizzled, 128B rows
  char* ldsP  = lds + 32768;    // 8 x 4KB: per-wave P[32 q][64 t] swizzled

  const int tid = threadIdx.x, w = tid >> 6, l = tid & 63;
  const int quad = l >> 4, l15 = l & 15;
  // XCD swizzle (bijective, 512 blocks): XCD k owns bh in [8k, 8k+8), all qt.
  const int lin = blockIdx.y * 8 + blockIdx.x;
  const int swz = (lin & 7) * 64 + (lin >> 3);
  const int qt = swz & 7, bh = swz >> 3;
  const int b = bh >> 4, h = bh & 15;
  const size_t rb = (size_t)b * SEQ;
  const int hc = h * HD;

  // Q fragments (B-operand): lane holds Q[q = q0+mt*16+l15][k = ks*32+quad*8+j]
  bf16x8 qf[2][2];
  const int q0 = qt * 256 + w * 32;
#pragma unroll
  for (int mt = 0; mt < 2; ++mt)
#pragma unroll
    for (int ks = 0; ks < 2; ++ks)
      qf[mt][ks] = *(const bf16x8*)(Qp + (rb + q0 + mt * 16 + l15) * DM + hc + ks * 32 + quad * 8);

  f32x4 o[2][4], l_acc[2];
#pragma unroll
  for (int mt = 0; mt < 2; ++mt) {
    l_acc[mt] = (f32x4){0.f, 0.f, 0.f, 0.f};
#pragma unroll
    for (int nt = 0; nt < 4; ++nt) o[mt][nt] = (f32x4){0.f, 0.f, 0.f, 0.f};
  }

  const int sc = ((l & 7) ^ (l >> 3)) * 8;     // K staging swizzle (elems)
  const float c2 = 0.045084220027780106f;      // (1/sqrt(1024)) * log2(e)
  char* prow = ldsP + w * 4096;                // wave-private P region

  const u16x8 ones_u = {0x3f80, 0x3f80, 0x3f80, 0x3f80, 0x3f80, 0x3f80, 0x3f80, 0x3f80};
  const bf16x8 ones = __builtin_bit_cast(bf16x8, ones_u);

  // preload tile 0 into buffer 0 (K: one gld_lds16/thread; V: row t=l, cols w*8..w*8+7)
  {
    gld_lds16(Kp + (rb + w * 8 + (l >> 3)) * DM + hc + sc, ldsK + w * 1024);
    u16x8 vr = *(const u16x8*)(Vp + (rb + l) * DM + hc + w * 8);
#pragma unroll
    for (int i = 0; i < 8; ++i) {
      int n = w * 8 + i;
      *(unsigned short*)(ldsVt + n * 128 + (((l >> 3) ^ i) * 16) + (l & 7) * 2) = vr[i];
    }
  }

  for (int kt = 0; kt < SEQ / 64; ++kt) {
    const int kb = kt & 1;
    char* ldsKb = ldsK + kb * 8192;
    char* ldsVb = ldsVt + kb * 8192;
    __syncthreads();   // staging of buf[kb] complete; all waves left iter kt-1

    // issue staging for kt+1 into the other buffer (latency hidden by compute)
    u16x8 vr;
    const bool pre = (kt < SEQ / 64 - 1);
    if (pre) {
      const size_t krow = rb + (size_t)(kt + 1) * 64;
      gld_lds16(Kp + (krow + w * 8 + (l >> 3)) * DM + hc + sc, ldsK + (kb ^ 1) * 8192 + w * 1024);
      vr = *(const u16x8*)(Vp + (krow + l) * DM + hc + w * 8);
    }

    // S^T = K Q^T : lane holds S^T[t=ct*16+quad*4+r][q=q0+mt*16+l15]
    f32x4 s[2][4];
#pragma unroll
    for (int mt = 0; mt < 2; ++mt)
#pragma unroll
      for (int ct = 0; ct < 4; ++ct) s[mt][ct] = (f32x4){0.f, 0.f, 0.f, 0.f};
    __builtin_amdgcn_s_setprio(1);
#pragma unroll
    for (int ks = 0; ks < 2; ++ks) {
      const int x = ((ks * 4 + quad) ^ (l15 & 7)) * 16;
      const char* kbase = ldsKb + l15 * 128 + x;
#pragma unroll
      for (int ct = 0; ct < 4; ++ct) {
        bf16x8 kf = *(const bf16x8*)(kbase + ct * 2048);
        s[0][ct] = __builtin_amdgcn_mfma_f32_16x16x32_bf16(kf, qf[0][ks], s[0][ct], 0, 0, 0);
        s[1][ct] = __builtin_amdgcn_mfma_f32_16x16x32_bf16(kf, qf[1][ks], s[1][ct], 0, 0, 0);
      }
    }
    __builtin_amdgcn_s_setprio(0);

    // fixed-max softmax: p = exp2(s*c2 - 2); truncation-pack; write P to LDS
#pragma unroll
    for (int mt = 0; mt < 2; ++mt) {
      char* pr = prow + (mt * 16 + l15) * 128;
      const int co = quad >> 1, bo = (quad & 1) * 8;
#pragma unroll
      for (int ct = 0; ct < 4; ++ct) {
        float p0 = fexp2(__builtin_fmaf(s[mt][ct][0], c2, -2.0f));
        float p1 = fexp2(__builtin_fmaf(s[mt][ct][1], c2, -2.0f));
        float p2 = fexp2(__builtin_fmaf(s[mt][ct][2], c2, -2.0f));
        float p3 = fexp2(__builtin_fmaf(s[mt][ct][3], c2, -2.0f));
        unsigned lo = pk_trunc(p0, p1), hi = pk_trunc(p2, p3);
        unsigned long long pw = (unsigned long long)lo | ((unsigned long long)hi << 32);
        int c = 2 * ct + co;   // t0 = ct*16 + quad*4 -> chunk
        *(unsigned long long*)(pr + ((c ^ (l15 & 7)) * 16) + bo) = pw;
      }
    }

    // O += P V ; l += P * ones (row-sum on the matrix pipe)
    __builtin_amdgcn_s_setprio(1);
#pragma unroll
    for (int ks = 0; ks < 2; ++ks) {
      const int x = ((ks * 4 + quad) ^ (l15 & 7)) * 16;
      const char* pbase = prow + l15 * 128 + x;
      const char* vbase = ldsVb + l15 * 128 + x;
      bf16x8 pf0 = *(const bf16x8*)(pbase);
      bf16x8 pf1 = *(const bf16x8*)(pbase + 2048);
      l_acc[0] = __builtin_amdgcn_mfma_f32_16x16x32_bf16(pf0, ones, l_acc[0], 0, 0, 0);
      l_acc[1] = __builtin_amdgcn_mfma_f32_16x16x32_bf16(pf1, ones, l_acc[1], 0, 0, 0);
#pragma unroll
      for (int nt = 0; nt < 4; ++nt) {
        bf16x8 vf = *(const bf16x8*)(vbase + nt * 2048);
        o[0][nt] = __builtin_amdgcn_mfma_f32_16x16x32_bf16(pf0, vf, o[0][nt], 0, 0, 0);
        o[1][nt] = __builtin_amdgcn_mfma_f32_16x16x32_bf16(pf1, vf, o[1][nt], 0, 0, 0);
      }
    }
    __builtin_amdgcn_s_setprio(0);

    // transpose-write V(kt+1) into the other buffer (safe: all waves past barrier kt)
    if (pre) {
      char* vb = ldsVt + (kb ^ 1) * 8192;
#pragma unroll
      for (int i = 0; i < 8; ++i) {
        int n = w * 8 + i;
        *(unsigned short*)(vb + n * 128 + (((l >> 3) ^ i) * 16) + (l & 7) * 2) = vr[i];
      }
    }
  }

  // epilogue: normalize by l (ones-B makes all 16 output cols identical in l_acc)
#pragma unroll
  for (int mt = 0; mt < 2; ++mt) {
#pragma unroll
    for (int r = 0; r < 4; ++r) {
      float inv = 1.f / l_acc[mt][r];
      size_t row = rb + q0 + mt * 16 + quad * 4 + r;
#pragma unroll
      for (int nt = 0; nt < 4; ++nt)
        Ctx[row * DM + hc + nt * 16 + l15] = f2bf(o[mt][nt][r] * inv);
    }
  }
}

// ---------------- launch ----------------
extern "C" void kernel_launch(void* const* d_in, const int* in_sizes, int n_in,
                              void* d_out, int out_size, void* d_ws, size_t ws_size,
                              hipStream_t stream) {
  const float* query  = (const float*)d_in[0];
  const float* key_in = (const float*)d_in[1];
  const float* value  = (const float*)d_in[2];
  const float* Wq = (const float*)d_in[3];
  const float* Wk = (const float*)d_in[4];
  const float* Wv = (const float*)d_in[5];
  const float* Wo = (const float*)d_in[6];
  const float* bo = (const float*)d_in[7];
  float* out = (float*)d_out;

  unsigned short* ws = (unsigned short*)d_ws;
  const size_t NT = (size_t)MR * DM;   // 8388608 elems
  unsigned short* Xq  = ws;
  unsigned short* Xk  = Xq + NT;
  unsigned short* Xv  = Xk + NT;
  unsigned short* Wt  = Xv + NT;              // 3 * 1M
  unsigned short* Wob = Wt + 3 * 1048576;     // 1M
  unsigned short* Qb  = Wob + 1048576;
  unsigned short* Kb  = Qb + NT;
  unsigned short* Vb  = Kb + NT;
  unsigned short* Cx  = Vb + NT;

  prep<<<dim3(4096, 1, 4), 256, 0, stream>>>(query, key_in, value, Xq, Xk, Xv,
                                             Wq, Wk, Wv, Wt, Wo, Wob);
  gemm_bt<true><<<dim3(8, 64, 3), 256, 0, stream>>>(Xq, Xk, Xv, Wt, Qb, nullptr);
  attn_flash<<<dim3(8, 64), 512, 0, stream>>>(Qb, Kb, Vb, Cx);
  gemm_bt<false><<<dim3(8, 64, 1), 256, 0, stream>>>(Cx, Cx, Cx, Wob, out, bo);
}